// Round 3
// baseline (816.645 us; speedup 1.0000x reference)
//
#include <hip/hip_runtime.h>
#include <math.h>

#define T_TOK 1024
#define E_EXP 8
#define H_DIM 2880
#define I_DIM 2880
#define NGU   5760      // 2*I
#define KB    90        // 2880/32
#define TM 128
#define TN 128
#define MAXROWS 3072

typedef __attribute__((ext_vector_type(8))) short short8;
typedef __attribute__((ext_vector_type(4))) float f32x4;

#define PERM(a, b, s) __builtin_amdgcn_perm((uint)(a), (uint)(b), (uint)(s))

// ---- workspace layout (bytes) ----
#define XQ_OFF   0ull                    // T*H bf16 = 5898240
#define ACT_OFF  5898240ull              // MAXROWS*I bf16 = 17694720
#define RTOK_OFF 23592960ull             // MAXROWS int
#define RW_OFF   23605248ull             // MAXROWS float
#define EB_OFF   23617536ull             // 8 int
#define EPC_OFF  23617568ull             // 8 int
#define CGU_OFF  23617664ull             // compact gate_up blocks: 66355200 B
#define CGS_OFF  89972864ull             // compact gate_up scales: 4147200 B
#define CDB_OFF  94120064ull             // compact down blocks: 33177600 B
#define CDS_OFF  127297664ull            // compact down scales: 2073600 B
#define WS_NEED  129371264ull

__device__ inline ushort f2bf(float f) {
  unsigned u = __float_as_uint(f);
  unsigned r = u + 0x7FFFu + ((u >> 16) & 1u);
  return (ushort)(r >> 16);
}

// e = clip(ceil(log2(max(amax,1e-12))), -127, 128)
__device__ inline int blk_exp(float amax) {
  amax = fmaxf(amax, 1e-12f);
  unsigned b = __float_as_uint(amax);
  int e = (int)(b >> 23) - 127;
  if (b & 0x7FFFFFu) e += 1;
  return min(max(e, -127), 128);
}

// quantize v*2^-eblk to fp8 e4m3 (RNE, subnormal lsb 2^-9), dequantize back.
__device__ inline float qdq_val(float v, int eblk) {
  float av = fabsf(v);
  if (av == 0.f) return 0.f;
  int fl = (int)(__float_as_uint(av) >> 23) - 127 - eblk;
  int p = max(fl, -6) - 3;
  float step = ldexpf(1.f, p + eblk);
  return rintf(v / step) * step;
}

__device__ inline float fp4v(int n) {
  int mag = n & 7;
  float v;
  if (mag == 0) v = 0.f;
  else if (mag == 1) v = 0.5f;
  else v = ldexpf(1.0f + 0.5f * (float)(mag & 1), (mag >> 1) - 1);
  return (n & 8) ? -v : v;
}

// old-path decode (LUT), kept for ws-too-small fallback
__device__ inline uint dec_byte(const float2* lut, int b, float sc) {
  float2 l = lut[b & 255];
  uint lo = __float_as_uint(l.x * sc);
  uint hi = __float_as_uint(l.y * sc);
  return PERM(hi, lo, 0x07060302u);
}

// ---- LUT-free decode: per-kb scaled byte tables + v_perm lookups ----
struct BTbl { uint tlo_l, tlo_h, thi_l, thi_h; };

__device__ inline BTbl build_tbl(float sc) {
  // exact products (fp4 mags have <=2 mantissa bits); bf16 = f32 truncation
  uint g0 = 0u;
  uint g1 = __float_as_uint(0.5f * sc);
  uint g2 = __float_as_uint(sc);
  uint g3 = __float_as_uint(1.5f * sc);
  uint g4 = __float_as_uint(2.0f * sc);
  uint g5 = __float_as_uint(3.0f * sc);
  uint g6 = __float_as_uint(4.0f * sc);
  uint g7 = __float_as_uint(6.0f * sc);
  uint p01 = PERM(g1, g0, 0x07030602u);  // [g0b2,g1b2,g0b3,g1b3]
  uint p23 = PERM(g3, g2, 0x07030602u);
  uint p45 = PERM(g5, g4, 0x07030602u);
  uint p67 = PERM(g7, g6, 0x07030602u);
  BTbl t;
  t.tlo_l = PERM(p23, p01, 0x05040100u);  // low bytes of bf16, mags 0..3
  t.thi_l = PERM(p23, p01, 0x07060302u);  // high bytes, mags 0..3
  t.tlo_h = PERM(p67, p45, 0x05040100u);  // mags 4..7
  t.thi_h = PERM(p67, p45, 0x07060302u);
  return t;
}

// decode 4 weight bytes (8 fp4) -> 8 bf16 in permuted-k order:
// [k0,k2,k4,k6, k1,k3,k5,k7] (evens = low nibbles first).
__device__ inline uint4 dec_w(uint w, const BTbl& t) {
  uint ml = w & 0x07070707u;
  uint mh = (w >> 4) & 0x07070707u;
  uint sl = (w << 4) & 0x80808080u;
  uint sh = w & 0x80808080u;
  uint hl = PERM(t.thi_h, t.thi_l, ml) | sl;
  uint hh = PERM(t.thi_h, t.thi_l, mh) | sh;
  uint ll = PERM(t.tlo_h, t.tlo_l, ml);
  uint lh = PERM(t.tlo_h, t.tlo_l, mh);
  uint4 o;
  o.x = PERM(hl, ll, 0x05010400u);  // [k0,k2]
  o.y = PERM(hl, ll, 0x07030602u);  // [k4,k6]
  o.z = PERM(hh, lh, 0x05010400u);  // [k1,k3]
  o.w = PERM(hh, lh, 0x07030602u);  // [k5,k7]
  return o;
}

// apply the same k-permutation to 8 natural-order bf16 (one uint4)
__device__ inline uint4 aperm(uint4 u) {
  uint4 v;
  v.x = PERM(u.y, u.x, 0x05040100u);  // [e0,e2]
  v.y = PERM(u.w, u.z, 0x05040100u);  // [e4,e6]
  v.z = PERM(u.y, u.x, 0x07060302u);  // [e1,e3]
  v.w = PERM(u.w, u.z, 0x07060302u);  // [e5,e7]
  return v;
}

// ---------------- repack: int32-per-byte -> packed bytes ----------------
__global__ void repack_kernel(const int* __restrict__ src, uint4* __restrict__ dst, int n16) {
  int g = blockIdx.x * 256 + threadIdx.x;
  if (g >= n16) return;
  const int4* s = (const int4*)(src) + g * 4;
  int4 w0 = s[0], w1 = s[1], w2 = s[2], w3 = s[3];
  uint4 o;
  o.x = (uint)(w0.x & 255) | ((uint)(w0.y & 255) << 8) | ((uint)(w0.z & 255) << 16) | ((uint)(w0.w) << 24);
  o.y = (uint)(w1.x & 255) | ((uint)(w1.y & 255) << 8) | ((uint)(w1.z & 255) << 16) | ((uint)(w1.w) << 24);
  o.z = (uint)(w2.x & 255) | ((uint)(w2.y & 255) << 8) | ((uint)(w2.z & 255) << 16) | ((uint)(w2.w) << 24);
  o.w = (uint)(w3.x & 255) | ((uint)(w3.y & 255) << 8) | ((uint)(w3.z & 255) << 16) | ((uint)(w3.w) << 24);
  dst[g] = o;
}

// ---------------- kernel 1: mxfp8 qdq of hidden_states -> bf16 ----------------
__global__ void quant_x_kernel(const float* __restrict__ x, ushort* __restrict__ xq) {
  int g = blockIdx.x * 256 + threadIdx.x;
  float4 v4 = ((const float4*)x)[g];
  float am = fmaxf(fmaxf(fabsf(v4.x), fabsf(v4.y)), fmaxf(fabsf(v4.z), fabsf(v4.w)));
  am = fmaxf(am, __shfl_xor(am, 1));
  am = fmaxf(am, __shfl_xor(am, 2));
  am = fmaxf(am, __shfl_xor(am, 4));
  int eb = blk_exp(am);
  ushort4 o;
  o.x = f2bf(qdq_val(v4.x, eb));
  o.y = f2bf(qdq_val(v4.y, eb));
  o.z = f2bf(qdq_val(v4.z, eb));
  o.w = f2bf(qdq_val(v4.w, eb));
  ((ushort4*)xq)[g] = o;
}

// ---------------- kernel 2: routing ----------------
__global__ void routing_kernel(const int* __restrict__ eidx, const float* __restrict__ rwt,
                               int* __restrict__ rtok, float* __restrict__ rw,
                               int* __restrict__ ebase, int* __restrict__ epc) {
  __shared__ int cnt[E_EXP];
  __shared__ int base_s[E_EXP];
  __shared__ int pos[E_EXP];
  int t = threadIdx.x;
  if (t < E_EXP) cnt[t] = 0;
  __syncthreads();
  for (int p = t; p < T_TOK * 2; p += 256) atomicAdd(&cnt[eidx[p]], 1);
  __syncthreads();
  if (t == 0) {
    int b = 0;
    for (int e = 0; e < E_EXP; e++) {
      base_s[e] = b;
      b += ((cnt[e] + TM - 1) / TM) * TM;
    }
  }
  __syncthreads();
  if (t < E_EXP) {
    pos[t] = 0;
    ebase[t] = base_s[t];
    epc[t] = ((cnt[t] + TM - 1) / TM) * TM;
  }
  __syncthreads();
  for (int p = t; p < T_TOK * 2; p += 256) {
    int e = eidx[p];
    int o = atomicAdd(&pos[e], 1);
    rtok[base_s[e] + o] = p >> 1;
    rw[base_s[e] + o] = rwt[p];
  }
  __syncthreads();
  for (int e = 0; e < E_EXP; e++) {
    int c = cnt[e], pc = ((c + TM - 1) / TM) * TM;
    for (int i = c + t; i < pc; i += 256) {
      rtok[base_s[e] + i] = 0;
      rw[base_s[e] + i] = 0.f;
    }
  }
}

// ---------------- GEMM1 compact: xq @ Wgu^T -> swiglu -> qdq -> act ----------------
__global__ __launch_bounds__(256, 2)
void gemm1c_kernel(const ushort* __restrict__ xq,
                   const uchar* __restrict__ cgu, const uchar* __restrict__ cgs,
                   const float* __restrict__ gubias,
                   const int* __restrict__ rtok, const int* __restrict__ ebase,
                   const int* __restrict__ epc,
                   ushort* __restrict__ act) {
  const int ntile = blockIdx.x;
  const int e = blockIdx.y >> 4;
  const int mtile = blockIdx.y & 15;
  if (mtile * TM >= epc[e]) return;
  const int rowbase = ebase[e] + mtile * TM;

  __shared__ __align__(16) ushort lA[TM][40];
  __shared__ __align__(16) ushort lB[TN][40];

  const int tid = threadIdx.x;
  const int wave = tid >> 6, lane = tid & 63;
  const int half = tid & 1, srow = tid >> 1;
  const int wm = (wave & 1) * 64, wn = (wave >> 1) * 64;
  const int lrow = lane & 15, q = lane >> 4;

  const int tokA = rtok[rowbase + srow];
  const ushort* aSrc = xq + tokA * H_DIM + half * 16;
  const int nrow = ntile * TN + srow;
  const uchar* bSrc = cgu + (size_t)(e * NGU + nrow) * 1440 + half * 8;
  const uchar* sSrc = cgs + (size_t)(e * NGU + nrow) * KB;

  f32x4 acc[4][4];
#pragma unroll
  for (int i = 0; i < 4; i++)
#pragma unroll
    for (int j = 0; j < 4; j++) acc[i][j] = (f32x4){0.f, 0.f, 0.f, 0.f};

  uint4 a0 = ((const uint4*)(aSrc))[0];
  uint4 a1 = ((const uint4*)(aSrc))[1];
  uint2 bw = *(const uint2*)(bSrc);
  uchar sb = sSrc[0];

  for (int kb = 0; kb < KB; kb++) {
    const int nk = (kb + 1 < KB) ? kb + 1 : kb;
    uint4 na0 = ((const uint4*)(aSrc + nk * 32))[0];
    uint4 na1 = ((const uint4*)(aSrc + nk * 32))[1];
    uint2 nbw = *(const uint2*)(bSrc + nk * 16);
    uchar nsb = sSrc[nk];

    float sc = ldexpf(1.f, (int)sb - 127);
    BTbl t = build_tbl(sc);
    uint4 d0 = dec_w(bw.x, t);
    uint4 d1 = dec_w(bw.y, t);
    uint4 pa0 = aperm(a0);
    uint4 pa1 = aperm(a1);

    __syncthreads();
    *(uint4*)&lA[srow][half * 16] = pa0;
    *(uint4*)&lA[srow][half * 16 + 8] = pa1;
    *(uint4*)&lB[srow][half * 16] = d0;
    *(uint4*)&lB[srow][half * 16 + 8] = d1;
    __syncthreads();

    short8 af[4], bfr[4];
#pragma unroll
    for (int mi = 0; mi < 4; mi++) af[mi] = *(const short8*)&lA[wm + mi * 16 + lrow][q * 8];
#pragma unroll
    for (int ni = 0; ni < 4; ni++) bfr[ni] = *(const short8*)&lB[wn + ni * 16 + lrow][q * 8];
#pragma unroll
    for (int mi = 0; mi < 4; mi++)
#pragma unroll
      for (int ni = 0; ni < 4; ni++)
        acc[mi][ni] = __builtin_amdgcn_mfma_f32_16x16x32_bf16(af[mi], bfr[ni], acc[mi][ni], 0, 0, 0);

    a0 = na0; a1 = na1; bw = nbw; sb = nsb;
  }

  const int nbase = ntile * TN + wn;
  float bias_v[4];
#pragma unroll
  for (int ni = 0; ni < 4; ni++) bias_v[ni] = gubias[e * NGU + nbase + ni * 16 + lrow];
  const bool evenl = (lane & 1) == 0;
#pragma unroll
  for (int mi = 0; mi < 4; mi++) {
    float av[4][4];
#pragma unroll
    for (int ni = 0; ni < 4; ni++)
#pragma unroll
      for (int r = 0; r < 4; r++) {
        float h = acc[mi][ni][r] + bias_v[ni];
        float pp = __shfl_xor(h, 1);
        float gate = evenl ? h : pp;
        float up = evenl ? pp : h;
        gate = fminf(gate, 7.f);
        up = fminf(fmaxf(up, -7.f), 7.f);
        float glu = gate / (1.f + expf(-1.702f * gate));
        av[ni][r] = (up + 1.f) * glu;
      }
#pragma unroll
    for (int r = 0; r < 4; r++) {
      float am = 0.f;
#pragma unroll
      for (int ni = 0; ni < 4; ni++) am = fmaxf(am, fabsf(av[ni][r]));
      am = fmaxf(am, __shfl_xor(am, 2));
      am = fmaxf(am, __shfl_xor(am, 4));
      am = fmaxf(am, __shfl_xor(am, 8));
      int eb = blk_exp(am);
      if (evenl) {
        int row = rowbase + wm + mi * 16 + q * 4 + r;
        int cb = (nbase >> 1) + (lrow >> 1);
#pragma unroll
        for (int ni = 0; ni < 4; ni++)
          act[row * I_DIM + cb + ni * 8] = f2bf(qdq_val(av[ni][r], eb));
      }
    }
  }
}

// ---------------- GEMM2 compact: act @ Wd^T -> *rw -> atomic scatter ----------------
__global__ __launch_bounds__(256, 2)
void gemm2c_kernel(const ushort* __restrict__ act,
                   const uchar* __restrict__ cdb, const uchar* __restrict__ cds,
                   const float* __restrict__ dbias,
                   const int* __restrict__ rtok, const float* __restrict__ rw,
                   const int* __restrict__ ebase, const int* __restrict__ epc,
                   float* __restrict__ out) {
  const int ntile = blockIdx.x;
  const int e = blockIdx.y >> 4;
  const int mtile = blockIdx.y & 15;
  if (mtile * TM >= epc[e]) return;
  const int rowbase = ebase[e] + mtile * TM;
  const int kz = blockIdx.z;
  const int kb0 = kz * (KB / 2), kb1 = kb0 + (KB / 2);

  __shared__ __align__(16) ushort lA[TM][40];
  __shared__ __align__(16) ushort lB[TN][40];

  const int tid = threadIdx.x;
  const int wave = tid >> 6, lane = tid & 63;
  const int half = tid & 1, srow = tid >> 1;
  const int wm = (wave & 1) * 64, wn = (wave >> 1) * 64;
  const int lrow = lane & 15, q = lane >> 4;

  const ushort* aSrc = act + (size_t)(rowbase + srow) * I_DIM + half * 16;
  int nrow = ntile * TN + srow;
  if (nrow >= H_DIM) nrow = H_DIM - 1;
  const uchar* bSrc = cdb + (size_t)(e * H_DIM + nrow) * 1440 + half * 8;
  const uchar* sSrc = cds + (size_t)(e * H_DIM + nrow) * KB;

  f32x4 acc[4][4];
#pragma unroll
  for (int i = 0; i < 4; i++)
#pragma unroll
    for (int j = 0; j < 4; j++) acc[i][j] = (f32x4){0.f, 0.f, 0.f, 0.f};

  uint4 a0 = ((const uint4*)(aSrc + kb0 * 32))[0];
  uint4 a1 = ((const uint4*)(aSrc + kb0 * 32))[1];
  uint2 bw = *(const uint2*)(bSrc + kb0 * 16);
  uchar sb = sSrc[kb0];

  for (int kb = kb0; kb < kb1; kb++) {
    const int nk = (kb + 1 < kb1) ? kb + 1 : kb;
    uint4 na0 = ((const uint4*)(aSrc + nk * 32))[0];
    uint4 na1 = ((const uint4*)(aSrc + nk * 32))[1];
    uint2 nbw = *(const uint2*)(bSrc + nk * 16);
    uchar nsb = sSrc[nk];

    float sc = ldexpf(1.f, (int)sb - 127);
    BTbl t = build_tbl(sc);
    uint4 d0 = dec_w(bw.x, t);
    uint4 d1 = dec_w(bw.y, t);
    uint4 pa0 = aperm(a0);
    uint4 pa1 = aperm(a1);

    __syncthreads();
    *(uint4*)&lA[srow][half * 16] = pa0;
    *(uint4*)&lA[srow][half * 16 + 8] = pa1;
    *(uint4*)&lB[srow][half * 16] = d0;
    *(uint4*)&lB[srow][half * 16 + 8] = d1;
    __syncthreads();

    short8 af[4], bfr[4];
#pragma unroll
    for (int mi = 0; mi < 4; mi++) af[mi] = *(const short8*)&lA[wm + mi * 16 + lrow][q * 8];
#pragma unroll
    for (int ni = 0; ni < 4; ni++) bfr[ni] = *(const short8*)&lB[wn + ni * 16 + lrow][q * 8];
#pragma unroll
    for (int mi = 0; mi < 4; mi++)
#pragma unroll
      for (int ni = 0; ni < 4; ni++)
        acc[mi][ni] = __builtin_amdgcn_mfma_f32_16x16x32_bf16(af[mi], bfr[ni], acc[mi][ni], 0, 0, 0);

    a0 = na0; a1 = na1; bw = nbw; sb = nsb;
  }

  const int nbase = ntile * TN + wn;
  float bias_v[4];
#pragma unroll
  for (int ni = 0; ni < 4; ni++) {
    int n = nbase + ni * 16 + lrow;
    bias_v[ni] = (kz == 0 && n < H_DIM) ? dbias[e * H_DIM + n] : 0.f;
  }
#pragma unroll
  for (int mi = 0; mi < 4; mi++)
#pragma unroll
    for (int r = 0; r < 4; r++) {
      int orow = rowbase + wm + mi * 16 + q * 4 + r;
      int tok = rtok[orow];
      float w = rw[orow];
      if (w != 0.f) {
#pragma unroll
        for (int ni = 0; ni < 4; ni++) {
          int n = nbase + ni * 16 + lrow;
          if (n < H_DIM) atomicAdd(&out[tok * H_DIM + n], w * (acc[mi][ni][r] + bias_v[ni]));
        }
      }
    }
}

// ================= fallback (ws too small): round-2 kernels =================
__global__ __launch_bounds__(256, 2)
void gemm1_kernel(const ushort* __restrict__ xq,
                  const int* __restrict__ gub, const int* __restrict__ gus,
                  const float* __restrict__ gubias,
                  const int* __restrict__ rtok, const int* __restrict__ ebase,
                  const int* __restrict__ epc,
                  ushort* __restrict__ act) {
  const int ntile = blockIdx.x;
  const int e = blockIdx.y >> 4;
  const int mtile = blockIdx.y & 15;
  if (mtile * TM >= epc[e]) return;
  const int rowbase = ebase[e] + mtile * TM;

  __shared__ __align__(16) ushort lA[TM][40];
  __shared__ __align__(16) ushort lB[TN][40];
  __shared__ float2 lut[256];

  const int tid = threadIdx.x;
  lut[tid] = make_float2(fp4v(tid & 15), fp4v((tid >> 4) & 15));
  __syncthreads();

  const int wave = tid >> 6, lane = tid & 63;
  const int half = tid & 1, srow = tid >> 1;
  const int wm = (wave & 1) * 64, wn = (wave >> 1) * 64;
  const int lrow = lane & 15, q = lane >> 4;

  const int tokA = rtok[rowbase + srow];
  const ushort* aSrc = xq + tokA * H_DIM + half * 16;
  const int nrow = ntile * TN + srow;
  const int* bSrc = gub + ((e * NGU + nrow) * KB) * 16 + half * 8;
  const int* sSrc = gus + (e * NGU + nrow) * KB;

  f32x4 acc[4][4];
#pragma unroll
  for (int i = 0; i < 4; i++)
#pragma unroll
    for (int j = 0; j < 4; j++) acc[i][j] = (f32x4){0.f, 0.f, 0.f, 0.f};

  for (int kb = 0; kb < KB; kb++) {
    uint4 a0 = ((const uint4*)(aSrc + kb * 32))[0];
    uint4 a1 = ((const uint4*)(aSrc + kb * 32))[1];
    int4 b0 = ((const int4*)(bSrc + kb * 16))[0];
    int4 b1 = ((const int4*)(bSrc + kb * 16))[1];
    float sc = ldexpf(1.f, sSrc[kb] - 127);
    int bv[8] = {b0.x, b0.y, b0.z, b0.w, b1.x, b1.y, b1.z, b1.w};
    uint us[8];
#pragma unroll
    for (int j = 0; j < 8; j++) us[j] = dec_byte(lut, bv[j], sc);
    __syncthreads();
    *(uint4*)&lA[srow][half * 16] = a0;
    *(uint4*)&lA[srow][half * 16 + 8] = a1;
    uint4 w0; w0.x = us[0]; w0.y = us[1]; w0.z = us[2]; w0.w = us[3];
    uint4 w1; w1.x = us[4]; w1.y = us[5]; w1.z = us[6]; w1.w = us[7];
    *(uint4*)&lB[srow][half * 16] = w0;
    *(uint4*)&lB[srow][half * 16 + 8] = w1;
    __syncthreads();
    short8 af[4], bfr[4];
#pragma unroll
    for (int mi = 0; mi < 4; mi++) af[mi] = *(const short8*)&lA[wm + mi * 16 + lrow][q * 8];
#pragma unroll
    for (int ni = 0; ni < 4; ni++) bfr[ni] = *(const short8*)&lB[wn + ni * 16 + lrow][q * 8];
#pragma unroll
    for (int mi = 0; mi < 4; mi++)
#pragma unroll
      for (int ni = 0; ni < 4; ni++)
        acc[mi][ni] = __builtin_amdgcn_mfma_f32_16x16x32_bf16(af[mi], bfr[ni], acc[mi][ni], 0, 0, 0);
  }

  const int nbase = ntile * TN + wn;
  float bias_v[4];
#pragma unroll
  for (int ni = 0; ni < 4; ni++) bias_v[ni] = gubias[e * NGU + nbase + ni * 16 + lrow];
  const bool evenl = (lane & 1) == 0;
#pragma unroll
  for (int mi = 0; mi < 4; mi++) {
    float av[4][4];
#pragma unroll
    for (int ni = 0; ni < 4; ni++)
#pragma unroll
      for (int r = 0; r < 4; r++) {
        float h = acc[mi][ni][r] + bias_v[ni];
        float pp = __shfl_xor(h, 1);
        float gate = evenl ? h : pp;
        float up = evenl ? pp : h;
        gate = fminf(gate, 7.f);
        up = fminf(fmaxf(up, -7.f), 7.f);
        float glu = gate / (1.f + expf(-1.702f * gate));
        av[ni][r] = (up + 1.f) * glu;
      }
#pragma unroll
    for (int r = 0; r < 4; r++) {
      float am = 0.f;
#pragma unroll
      for (int ni = 0; ni < 4; ni++) am = fmaxf(am, fabsf(av[ni][r]));
      am = fmaxf(am, __shfl_xor(am, 2));
      am = fmaxf(am, __shfl_xor(am, 4));
      am = fmaxf(am, __shfl_xor(am, 8));
      int eb = blk_exp(am);
      if (evenl) {
        int row = rowbase + wm + mi * 16 + q * 4 + r;
        int cb = (nbase >> 1) + (lrow >> 1);
#pragma unroll
        for (int ni = 0; ni < 4; ni++)
          act[row * I_DIM + cb + ni * 8] = f2bf(qdq_val(av[ni][r], eb));
      }
    }
  }
}

__global__ __launch_bounds__(256, 2)
void gemm2_kernel(const ushort* __restrict__ act,
                  const int* __restrict__ db, const int* __restrict__ dsc,
                  const float* __restrict__ dbias,
                  const int* __restrict__ rtok, const float* __restrict__ rw,
                  const int* __restrict__ ebase, const int* __restrict__ epc,
                  float* __restrict__ out) {
  const int ntile = blockIdx.x;
  const int e = blockIdx.y >> 4;
  const int mtile = blockIdx.y & 15;
  if (mtile * TM >= epc[e]) return;
  const int rowbase = ebase[e] + mtile * TM;
  const int kz = blockIdx.z;
  const int kb0 = kz * (KB / 2), kb1 = kb0 + (KB / 2);

  __shared__ __align__(16) ushort lA[TM][40];
  __shared__ __align__(16) ushort lB[TN][40];
  __shared__ float2 lut[256];

  const int tid = threadIdx.x;
  lut[tid] = make_float2(fp4v(tid & 15), fp4v((tid >> 4) & 15));
  __syncthreads();

  const int wave = tid >> 6, lane = tid & 63;
  const int half = tid & 1, srow = tid >> 1;
  const int wm = (wave & 1) * 64, wn = (wave >> 1) * 64;
  const int lrow = lane & 15, q = lane >> 4;

  const ushort* aSrc = act + (rowbase + srow) * I_DIM + half * 16;
  int nrow = ntile * TN + srow;
  if (nrow >= H_DIM) nrow = H_DIM - 1;
  const int* bSrc = db + ((e * H_DIM + nrow) * KB) * 16 + half * 8;
  const int* sSrc = dsc + (e * H_DIM + nrow) * KB;

  f32x4 acc[4][4];
#pragma unroll
  for (int i = 0; i < 4; i++)
#pragma unroll
    for (int j = 0; j < 4; j++) acc[i][j] = (f32x4){0.f, 0.f, 0.f, 0.f};

  for (int kb = kb0; kb < kb1; kb++) {
    uint4 a0 = ((const uint4*)(aSrc + kb * 32))[0];
    uint4 a1 = ((const uint4*)(aSrc + kb * 32))[1];
    int4 b0 = ((const int4*)(bSrc + kb * 16))[0];
    int4 b1 = ((const int4*)(bSrc + kb * 16))[1];
    float sc = ldexpf(1.f, sSrc[kb] - 127);
    int bv[8] = {b0.x, b0.y, b0.z, b0.w, b1.x, b1.y, b1.z, b1.w};
    uint us[8];
#pragma unroll
    for (int j = 0; j < 8; j++) us[j] = dec_byte(lut, bv[j], sc);
    __syncthreads();
    *(uint4*)&lA[srow][half * 16] = a0;
    *(uint4*)&lA[srow][half * 16 + 8] = a1;
    uint4 w0; w0.x = us[0]; w0.y = us[1]; w0.z = us[2]; w0.w = us[3];
    uint4 w1; w1.x = us[4]; w1.y = us[5]; w1.z = us[6]; w1.w = us[7];
    *(uint4*)&lB[srow][half * 16] = w0;
    *(uint4*)&lB[srow][half * 16 + 8] = w1;
    __syncthreads();
    short8 af[4], bfr[4];
#pragma unroll
    for (int mi = 0; mi < 4; mi++) af[mi] = *(const short8*)&lA[wm + mi * 16 + lrow][q * 8];
#pragma unroll
    for (int ni = 0; ni < 4; ni++) bfr[ni] = *(const short8*)&lB[wn + ni * 16 + lrow][q * 8];
#pragma unroll
    for (int mi = 0; mi < 4; mi++)
#pragma unroll
      for (int ni = 0; ni < 4; ni++)
        acc[mi][ni] = __builtin_amdgcn_mfma_f32_16x16x32_bf16(af[mi], bfr[ni], acc[mi][ni], 0, 0, 0);
  }

  const int nbase = ntile * TN + wn;
  float bias_v[4];
#pragma unroll
  for (int ni = 0; ni < 4; ni++) {
    int n = nbase + ni * 16 + lrow;
    bias_v[ni] = (kz == 0 && n < H_DIM) ? dbias[e * H_DIM + n] : 0.f;
  }
#pragma unroll
  for (int mi = 0; mi < 4; mi++)
#pragma unroll
    for (int r = 0; r < 4; r++) {
      int orow = rowbase + wm + mi * 16 + q * 4 + r;
      int tok = rtok[orow];
      float w = rw[orow];
      if (w != 0.f) {
#pragma unroll
        for (int ni = 0; ni < 4; ni++) {
          int n = nbase + ni * 16 + lrow;
          if (n < H_DIM) atomicAdd(&out[tok * H_DIM + n], w * (acc[mi][ni][r] + bias_v[ni]));
        }
      }
    }
}

extern "C" void kernel_launch(void* const* d_in, const int* in_sizes, int n_in,
                              void* d_out, int out_size, void* d_ws, size_t ws_size,
                              hipStream_t stream) {
  const float* hs = (const float*)d_in[0];
  const int* eidx = (const int*)d_in[1];
  const float* rwt = (const float*)d_in[2];
  const int* gub = (const int*)d_in[3];
  const int* gus = (const int*)d_in[4];
  const float* gubias = (const float*)d_in[5];
  const int* db = (const int*)d_in[6];
  const int* dsc = (const int*)d_in[7];
  const float* dbias = (const float*)d_in[8];
  float* out = (float*)d_out;
  char* ws = (char*)d_ws;

  ushort* xq = (ushort*)(ws + XQ_OFF);
  ushort* act = (ushort*)(ws + ACT_OFF);
  int* rtok = (int*)(ws + RTOK_OFF);
  float* rw = (float*)(ws + RW_OFF);
  int* ebase = (int*)(ws + EB_OFF);
  int* epc = (int*)(ws + EPC_OFF);

  hipMemsetAsync(d_out, 0, (size_t)out_size * sizeof(float), stream);
  quant_x_kernel<<<2880, 256, 0, stream>>>(hs, xq);
  routing_kernel<<<1, 256, 0, stream>>>(eidx, rwt, rtok, rw, ebase, epc);

  if (ws_size >= WS_NEED) {
    uchar* cgu = (uchar*)(ws + CGU_OFF);
    uchar* cgs = (uchar*)(ws + CGS_OFF);
    uchar* cdb = (uchar*)(ws + CDB_OFF);
    uchar* cds = (uchar*)(ws + CDS_OFF);
    repack_kernel<<<16200, 256, 0, stream>>>(gub, (uint4*)cgu, 4147200);
    repack_kernel<<<8100, 256, 0, stream>>>(db, (uint4*)cdb, 2073600);
    repack_kernel<<<1013, 256, 0, stream>>>(gus, (uint4*)cgs, 259200);
    repack_kernel<<<507, 256, 0, stream>>>(dsc, (uint4*)cds, 129600);
    gemm1c_kernel<<<dim3(45, 128), 256, 0, stream>>>(xq, cgu, cgs, gubias, rtok, ebase, epc, act);
    gemm2c_kernel<<<dim3(23, 128, 2), 256, 0, stream>>>(act, cdb, cds, dbias, rtok, rw, ebase, epc, out);
  } else {
    gemm1_kernel<<<dim3(45, 128), 256, 0, stream>>>(xq, gub, gus, gubias, rtok, ebase, epc, act);
    gemm2_kernel<<<dim3(23, 128, 2), 256, 0, stream>>>(act, db, dsc, dbias, rtok, rw, ebase, epc, out);
  }
}